// Round 11
// baseline (167.210 us; speedup 1.0000x reference)
//
#include <hip/hip_runtime.h>
#include <hip/hip_bf16.h>

// Problem constants
#define NT      32      // time steps
#define FEAT    128     // in/out features per step
#define TRIB    8       // band width in blocks
#define BATCH   8192
#define INSIZE  (NT*FEAT)   // 4096
#define OUTCOLS (NT*FEAT)   // 4096

typedef __bf16 bf16;
typedef __bf16 bf16x4 __attribute__((ext_vector_type(4)));
typedef __bf16 bf16x8 __attribute__((ext_vector_type(8)));
typedef float  f32x4  __attribute__((ext_vector_type(4)));

__host__ __device__ __forceinline__ int nb_of(int i){ return i < TRIB ? i + 1 : TRIB; }
__host__ __device__ __forceinline__ int lo_of(int i){ int l = i - TRIB + 1; return l > 0 ? l : 0; }
__host__ __device__ __forceinline__ long off_of(int i){
  long sum = (i <= TRIB) ? (long)i*(i+1)/2 : (long)(TRIB*(TRIB+1)/2) + (long)(i - TRIB)*TRIB;
  return sum * (long)(FEAT*FEAT);
}

// ---------------- W conversion (band only, ~15 MB read, ~5 us) ----------------
__global__ void cvt_w_kernel(const float* __restrict__ w, bf16* __restrict__ wp){
  int i = blockIdx.x;
  int n = blockIdx.y;
  int ktl = nb_of(i) * FEAT;
  int lo  = lo_of(i) * FEAT;
  long src = (long)(i*FEAT + n) * INSIZE + lo;
  long dst = off_of(i) + (long)n * ktl;
  for (int e = threadIdx.x * 4; e < ktl; e += blockDim.x * 4){
    f32x4 v = *(const f32x4*)(w + src + e);
    bf16x4 o;
    o.x = (bf16)v.x; o.y = (bf16)v.y; o.z = (bf16)v.z; o.w = (bf16)v.w;
    *(bf16x4*)(wp + dst + e) = o;
  }
}

// ------- banded GEMM R11: A staged as f32 via DMA (cvt_x eliminated) ---------
// BM=256, BN=128, BK=32. 256 threads = 4 waves (2M x 2N), wave tile 128x64.
// A (x, f32) staged via global_load_lds as f32 (32 KiB/stage), converted to
// bf16 IN REGISTER after ds_read. B (wp, packed bf16) staged as before
// (8 KiB/stage, superrow swizzle). Stage = 40 KiB; NSTAGE=2 -> 80 KiB/block
// -> 2 blocks/CU (160 KiB exact).
// Grid: XCD-chunked, i-FAST within chunk: XCD k owns mt in [4k,4k+4), i
// descending fast -> each mt's x f32 slice (4 MB) is read by its 8 sharing
// i-blocks while L2/L3-resident => x fetched ~once (fixes R7's 380 MB).
// A-f32 swizzle: 128-B rows, slot q = s ^ (row&7) (16-lane phases conflict-
// free); applied on pre-permuted global source + XOR'd read offsets.

#define BM 256
#define BN 128
#define BK 32
#define A_BYTES (BM*BK*4)            // 32768
#define B_BYTES_R (BN*BK*2)          // 8192
#define STAGE_BYTES (A_BYTES + B_BYTES_R)   // 40960

__device__ __forceinline__ void gload16(const void* g, void* l){
  __builtin_amdgcn_global_load_lds(
      (__attribute__((address_space(1))) unsigned int*)(unsigned long long)g,
      (__attribute__((address_space(3))) unsigned int*)l,
      16, 0, 0);
}

__device__ __forceinline__ unsigned lds_addr(void* p){
  return (unsigned)(unsigned long long)(__attribute__((address_space(3))) void*)p;
}

__device__ __forceinline__ bf16x8 ds_read16(unsigned addr){
  bf16x8 r;
  asm volatile("ds_read_b128 %0, %1" : "=&v"(r) : "v"(addr));
  return r;
}

__device__ __forceinline__ f32x4 ds_read16f(unsigned addr){
  f32x4 r;
  asm volatile("ds_read_b128 %0, %1" : "=&v"(r) : "v"(addr));
  return r;
}

__device__ __forceinline__ bf16x8 cvt8(f32x4 lo, f32x4 hi){
  bf16x8 o;
  o[0]=(bf16)lo.x; o[1]=(bf16)lo.y; o[2]=(bf16)lo.z; o[3]=(bf16)lo.w;
  o[4]=(bf16)hi.x; o[5]=(bf16)hi.y; o[6]=(bf16)hi.z; o[7]=(bf16)hi.w;
  return o;
}

__global__ __launch_bounds__(256, 2)
void gemm_band_kernel(const float* __restrict__ x, const bf16* __restrict__ wp,
                      const float* __restrict__ bias, float* __restrict__ out){
  __shared__ __align__(64) char ldsc[2 * STAGE_BYTES];   // 80 KiB

  // ---- XCD-chunked remap, i-FAST: xcd = bid&7; XCD k owns mt in [4k,4k+4).
  const int bid  = blockIdx.x;
  const int xcd  = bid & 7;
  const int idx  = bid >> 3;             // 0..127
  const int mloc = idx >> 5;             // 0..3 (slow within chunk)
  const int i    = 31 - (idx & 31);      // fast, descending (LPT)
  const int mt   = xcd * 4 + mloc;
  const int m0   = mt * BM;
  const int nbK  = nb_of(i);
  const int ntiles = nbK * (FEAT / BK);  // 4..32 K32-tiles
  const int lo   = lo_of(i) * FEAT;
  const int Kt   = nbK * FEAT;
  const long wpo = off_of(i);

  const int tid  = threadIdx.x;
  const int lane = tid & 63;
  const int wid  = tid >> 6;             // 0..3
  const int wr   = wid >> 1;             // 0..1 -> 128-row M strip
  const int wc   = wid & 1;              // 0..1 -> 64-col N strip
  const int fr   = lane & 15;
  const int ks   = lane >> 4;            // 0..3 k-slot (8 elems)

  const unsigned ldsBase = lds_addr((void*)ldsc);

  // -------- A read offsets: f32 rows = 128 B, slot q = (2ks)^(row&7) -------
  unsigned offAlo[8], offAhi[8];
  #pragma unroll
  for (int mi = 0; mi < 8; ++mi){
    const int row = wr*128 + mi*16 + fr;
    const unsigned q = (unsigned)((2*ks) ^ (row & 7));
    offAlo[mi] = (unsigned)row*128u + q*16u;
    offAhi[mi] = offAlo[mi] ^ 16u;       // slot q^1 (pair stays adjacent)
  }
  // -------- B read offsets: superrow-packed swizzle (R10 proven) -----------
  unsigned offB[4];
  #pragma unroll
  for (int ni = 0; ni < 4; ++ni){
    const int row = wc*64 + ni*16 + fr;
    const int u = row >> 1;
    const int q = (((row & 1) << 2) | ks) ^ (u & 7);
    offB[ni] = (unsigned)A_BYTES + (unsigned)(u*128 + q*16);
  }

  // -------- A staging: pre-permuted f32 source, linear LDS dest ------------
  // chunk c = j*256+tid (2048 total): row r = j*32+(tid>>3), slot s = tid&7,
  // global slot gs = s^(r&7) = (tid&7)^((tid>>3)&7) (uniform over j).
  const int gs = (tid & 7) ^ ((tid >> 3) & 7);
  const float* srcA0 = x + (long)(m0 + (tid >> 3)) * INSIZE + lo + gs*4;
  // -------- B staging: pre-permuted bf16 source (R10 verbatim) -------------
  const bf16* srcB[2];
  #pragma unroll
  for (int j = 0; j < 2; ++j){
    const int c = j*256 + tid;
    const int u = c >> 3, qq = c & 7;
    const int s8 = qq ^ (u & 7);
    const int r  = 2*u + (s8 >> 2);
    const int sb = s8 & 3;
    srcB[j] = wp + wpo + (long)r * Kt + sb*8;
  }

  auto stage = [&](char* base, int t){
    #pragma unroll
    for (int j = 0; j < 8; ++j)
      gload16(srcA0 + (long)j*32*INSIZE + t*BK, base + (j*256 + wid*64)*16);
    gload16(srcB[0] + t*BK, base + A_BYTES + (0*256 + wid*64)*16);
    gload16(srcB[1] + t*BK, base + A_BYTES + (1*256 + wid*64)*16);
  };

  // -------- prologue: stage tile 0 -----------------------------------------
  stage(ldsc, 0);
  f32x4 acc[8][4] = {};
  asm volatile("s_waitcnt vmcnt(0)" ::: "memory");
  __builtin_amdgcn_s_barrier();
  asm volatile("" ::: "memory");

  for (int t = 0; t < ntiles; ++t){
    const unsigned cA = ldsBase + (unsigned)(t & 1) * STAGE_BYTES;
    char* pb = ldsc + ((t & 1) ^ 1) * STAGE_BYTES;
    const bool pf = (t + 1 < ntiles);

    // ---- batch 1: A frags 0-3 (8 f32 reads) + B (4 reads)
    f32x4 ar[8];
    #pragma unroll
    for (int mi = 0; mi < 4; ++mi){
      ar[2*mi]   = ds_read16f(cA + offAlo[mi]);
      ar[2*mi+1] = ds_read16f(cA + offAhi[mi]);
    }
    bf16x8 b0 = ds_read16(cA + offB[0]);
    bf16x8 b1 = ds_read16(cA + offB[1]);
    bf16x8 b2 = ds_read16(cA + offB[2]);
    bf16x8 b3 = ds_read16(cA + offB[3]);

    // ---- issue next tile's staging into the other buffer (safe: everyone
    //      passed the end-of-(t-1) barrier after finishing reads of it)
    if (pf) stage(pb, t + 1);

    // ---- cluster 1: cvt + MFMA frags 0-3
    asm volatile("s_waitcnt lgkmcnt(0)" ::: "memory");
    __builtin_amdgcn_sched_barrier(0);
    {
      bf16x8 af0 = cvt8(ar[0], ar[1]);
      bf16x8 af1 = cvt8(ar[2], ar[3]);
      bf16x8 af2 = cvt8(ar[4], ar[5]);
      bf16x8 af3 = cvt8(ar[6], ar[7]);
      __builtin_amdgcn_s_setprio(1);
      acc[0][0] = __builtin_amdgcn_mfma_f32_16x16x32_bf16(af0, b0, acc[0][0], 0,0,0);
      acc[0][1] = __builtin_amdgcn_mfma_f32_16x16x32_bf16(af0, b1, acc[0][1], 0,0,0);
      acc[0][2] = __builtin_amdgcn_mfma_f32_16x16x32_bf16(af0, b2, acc[0][2], 0,0,0);
      acc[0][3] = __builtin_amdgcn_mfma_f32_16x16x32_bf16(af0, b3, acc[0][3], 0,0,0);
      acc[1][0] = __builtin_amdgcn_mfma_f32_16x16x32_bf16(af1, b0, acc[1][0], 0,0,0);
      acc[1][1] = __builtin_amdgcn_mfma_f32_16x16x32_bf16(af1, b1, acc[1][1], 0,0,0);
      acc[1][2] = __builtin_amdgcn_mfma_f32_16x16x32_bf16(af1, b2, acc[1][2], 0,0,0);
      acc[1][3] = __builtin_amdgcn_mfma_f32_16x16x32_bf16(af1, b3, acc[1][3], 0,0,0);
      acc[2][0] = __builtin_amdgcn_mfma_f32_16x16x32_bf16(af2, b0, acc[2][0], 0,0,0);
      acc[2][1] = __builtin_amdgcn_mfma_f32_16x16x32_bf16(af2, b1, acc[2][1], 0,0,0);
      acc[2][2] = __builtin_amdgcn_mfma_f32_16x16x32_bf16(af2, b2, acc[2][2], 0,0,0);
      acc[2][3] = __builtin_amdgcn_mfma_f32_16x16x32_bf16(af2, b3, acc[2][3], 0,0,0);
      acc[3][0] = __builtin_amdgcn_mfma_f32_16x16x32_bf16(af3, b0, acc[3][0], 0,0,0);
      acc[3][1] = __builtin_amdgcn_mfma_f32_16x16x32_bf16(af3, b1, acc[3][1], 0,0,0);
      acc[3][2] = __builtin_amdgcn_mfma_f32_16x16x32_bf16(af3, b2, acc[3][2], 0,0,0);
      acc[3][3] = __builtin_amdgcn_mfma_f32_16x16x32_bf16(af3, b3, acc[3][3], 0,0,0);
      __builtin_amdgcn_s_setprio(0);
    }

    // ---- batch 2: A frags 4-7 (8 f32 reads)
    #pragma unroll
    for (int mi = 0; mi < 4; ++mi){
      ar[2*mi]   = ds_read16f(cA + offAlo[4+mi]);
      ar[2*mi+1] = ds_read16f(cA + offAhi[4+mi]);
    }
    asm volatile("s_waitcnt lgkmcnt(0)" ::: "memory");
    __builtin_amdgcn_sched_barrier(0);
    {
      bf16x8 af4 = cvt8(ar[0], ar[1]);
      bf16x8 af5 = cvt8(ar[2], ar[3]);
      bf16x8 af6 = cvt8(ar[4], ar[5]);
      bf16x8 af7 = cvt8(ar[6], ar[7]);
      __builtin_amdgcn_s_setprio(1);
      acc[4][0] = __builtin_amdgcn_mfma_f32_16x16x32_bf16(af4, b0, acc[4][0], 0,0,0);
      acc[4][1] = __builtin_amdgcn_mfma_f32_16x16x32_bf16(af4, b1, acc[4][1], 0,0,0);
      acc[4][2] = __builtin_amdgcn_mfma_f32_16x16x32_bf16(af4, b2, acc[4][2], 0,0,0);
      acc[4][3] = __builtin_amdgcn_mfma_f32_16x16x32_bf16(af4, b3, acc[4][3], 0,0,0);
      acc[5][0] = __builtin_amdgcn_mfma_f32_16x16x32_bf16(af5, b0, acc[5][0], 0,0,0);
      acc[5][1] = __builtin_amdgcn_mfma_f32_16x16x32_bf16(af5, b1, acc[5][1], 0,0,0);
      acc[5][2] = __builtin_amdgcn_mfma_f32_16x16x32_bf16(af5, b2, acc[5][2], 0,0,0);
      acc[5][3] = __builtin_amdgcn_mfma_f32_16x16x32_bf16(af5, b3, acc[5][3], 0,0,0);
      acc[6][0] = __builtin_amdgcn_mfma_f32_16x16x32_bf16(af6, b0, acc[6][0], 0,0,0);
      acc[6][1] = __builtin_amdgcn_mfma_f32_16x16x32_bf16(af6, b1, acc[6][1], 0,0,0);
      acc[6][2] = __builtin_amdgcn_mfma_f32_16x16x32_bf16(af6, b2, acc[6][2], 0,0,0);
      acc[6][3] = __builtin_amdgcn_mfma_f32_16x16x32_bf16(af6, b3, acc[6][3], 0,0,0);
      acc[7][0] = __builtin_amdgcn_mfma_f32_16x16x32_bf16(af7, b0, acc[7][0], 0,0,0);
      acc[7][1] = __builtin_amdgcn_mfma_f32_16x16x32_bf16(af7, b1, acc[7][1], 0,0,0);
      acc[7][2] = __builtin_amdgcn_mfma_f32_16x16x32_bf16(af7, b2, acc[7][2], 0,0,0);
      acc[7][3] = __builtin_amdgcn_mfma_f32_16x16x32_bf16(af7, b3, acc[7][3], 0,0,0);
      __builtin_amdgcn_s_setprio(0);
    }

    // ---- single per-tile sync: my stage(t+1) retired + everyone ready
    if (pf){
      asm volatile("s_waitcnt vmcnt(0)" ::: "memory");
      __builtin_amdgcn_s_barrier();
      asm volatile("" ::: "memory");
    }
  }

  // -------- epilogue: C/D layout col = lane&15, row = (lane>>4)*4 + reg ----
  #pragma unroll
  for (int ni = 0; ni < 4; ++ni){
    const int gcol = i*FEAT + wc*64 + ni*16 + fr;
    const float bv = bias[gcol];
    #pragma unroll
    for (int mi = 0; mi < 8; ++mi){
      const int rbase = m0 + wr*128 + mi*16 + ks*4;
      #pragma unroll
      for (int r2 = 0; r2 < 4; ++r2)
        out[(long)(rbase + r2) * OUTCOLS + gcol] = acc[mi][ni][r2] + bv;
    }
  }
}

// ---------------- fallback (tiny ws): naive fp32, band-limited ----------------
__global__ void naive_kernel(const float* __restrict__ x, const float* __restrict__ w,
                             const float* __restrict__ bias, float* __restrict__ out){
  long idx = (long)blockIdx.x * blockDim.x + threadIdx.x;
  int o = (int)(idx & (OUTCOLS - 1));
  int b = (int)(idx >> 12);
  int i = o >> 7;
  int lo = lo_of(i) * FEAT, hi = (i + 1) * FEAT;
  const float* xr = x + (long)b * INSIZE;
  const float* wr = w + (long)o * INSIZE;
  float s = bias[o];
  for (int k = lo; k < hi; k += 4){
    f32x4 xv = *(const f32x4*)(xr + k);
    f32x4 wv = *(const f32x4*)(wr + k);
    s += xv.x*wv.x + xv.y*wv.y + xv.z*wv.z + xv.w*wv.w;
  }
  out[idx] = s;
}

// ---------------- launch ----------------
extern "C" void kernel_launch(void* const* d_in, const int* in_sizes, int n_in,
                              void* d_out, int out_size, void* d_ws, size_t ws_size,
                              hipStream_t stream) {
  const float* x    = (const float*)d_in[0];
  const float* w    = (const float*)d_in[1];
  const float* bias = (const float*)d_in[2];
  float* out = (float*)d_out;

  const size_t w_bytes = (size_t)228 * FEAT * FEAT * sizeof(bf16);     // ~7.5 MiB
  if (ws_size >= w_bytes){
    bf16* wp = (bf16*)d_ws;
    cvt_w_kernel<<<dim3(NT, FEAT), 256, 0, stream>>>(w, wp);
    gemm_band_kernel<<<dim3(NT * (BATCH/BM)), 256, 0, stream>>>(x, wp, bias, out);
  } else {
    naive_kernel<<<(long)BATCH * OUTCOLS / 256, 256, 0, stream>>>(x, w, bias, out);
  }
}

// Round 12
// 137.313 us; speedup vs baseline: 1.2177x; 1.2177x over previous
//
#include <hip/hip_runtime.h>
#include <hip/hip_bf16.h>

// Problem constants
#define NT      32      // time steps
#define FEAT    128     // in/out features per step
#define TRIB    8       // band width in blocks
#define BATCH   8192
#define INSIZE  (NT*FEAT)   // 4096
#define OUTCOLS (NT*FEAT)   // 4096

typedef __bf16 bf16;
typedef __bf16 bf16x4 __attribute__((ext_vector_type(4)));
typedef __bf16 bf16x8 __attribute__((ext_vector_type(8)));
typedef float  f32x4  __attribute__((ext_vector_type(4)));
typedef float  f32x16 __attribute__((ext_vector_type(16)));

__host__ __device__ __forceinline__ int nb_of(int i){ return i < TRIB ? i + 1 : TRIB; }
__host__ __device__ __forceinline__ int lo_of(int i){ int l = i - TRIB + 1; return l > 0 ? l : 0; }
__host__ __device__ __forceinline__ long off_of(int i){
  long sum = (i <= TRIB) ? (long)i*(i+1)/2 : (long)(TRIB*(TRIB+1)/2) + (long)(i - TRIB)*TRIB;
  return sum * (long)(FEAT*FEAT);
}

// ------------- merged conversion kernel: W-band + x in ONE launch -----------
// blocks [0, 4096): W band (i = bid>>7, n = bid&127) — verbatim proven body.
// blocks [4096, 6144): x f32->bf16, 2048-block grid-stride — verbatim body.
__global__ void cvt_kernel(const float* __restrict__ x, const float* __restrict__ w,
                           bf16* __restrict__ xb, bf16* __restrict__ wp, long n4x){
  const int bid = blockIdx.x;
  if (bid < NT*FEAT){
    const int i = bid >> 7;
    const int n = bid & 127;
    const int ktl = nb_of(i) * FEAT;
    const int lo  = lo_of(i) * FEAT;
    const long src = (long)(i*FEAT + n) * INSIZE + lo;
    const long dst = off_of(i) + (long)n * ktl;
    for (int e = threadIdx.x * 4; e < ktl; e += blockDim.x * 4){
      f32x4 v = *(const f32x4*)(w + src + e);
      bf16x4 o;
      o.x = (bf16)v.x; o.y = (bf16)v.y; o.z = (bf16)v.z; o.w = (bf16)v.w;
      *(bf16x4*)(wp + dst + e) = o;
    }
  } else {
    long idx = (long)(bid - NT*FEAT) * blockDim.x + threadIdx.x;
    long stride = 2048l * blockDim.x;
    const f32x4* src = (const f32x4*)x;
    bf16x4* dst = (bf16x4*)xb;
    for (long c = idx; c < n4x; c += stride){
      f32x4 v = src[c];
      bf16x4 o;
      o.x = (bf16)v.x; o.y = (bf16)v.y; o.z = (bf16)v.z; o.w = (bf16)v.w;
      dst[c] = o;
    }
  }
}

// ------- banded GEMM R12: R5 structure + 32x32x16 MFMA (2382-TF class) ------
// BM=512, BN=128, BK=32. 512 threads = 8 waves (4M x 2N), wave tile 128x64 =
// 4(M-frag 32) x 2(N-frag 32) of 32x32, acc = f32x16 x 8 = 128 regs (same as
// before). 16 MFMA/tile/wave (was 32) at the higher 32x32 rate ceiling.
// 3-stage LDS (120 KiB), free-run single barrier + counted vmcnt(5)/tile —
// the R5 champion schedule verbatim. Superrow-packed XOR swizzle (verified
// conflict-free for 32-lane stride-64B reads: u,u+8 pairs = 2-way = free).

#define BM 512
#define BN 128
#define BK 32
#define NSTAGE 3
#define A_ELEMS (BM*BK)              // 16384
#define B_ELEMS (BN*BK)              // 4096
#define TILE_ELEMS (A_ELEMS + B_ELEMS)

__device__ __forceinline__ void gload16(const void* g, void* l){
  __builtin_amdgcn_global_load_lds(
      (__attribute__((address_space(1))) unsigned int*)(unsigned long long)g,
      (__attribute__((address_space(3))) unsigned int*)l,
      16, 0, 0);
}

__device__ __forceinline__ unsigned lds_addr(void* p){
  return (unsigned)(unsigned long long)(__attribute__((address_space(3))) void*)p;
}

__device__ __forceinline__ bf16x8 ds_read16(unsigned addr){
  bf16x8 r;
  asm volatile("ds_read_b128 %0, %1" : "=&v"(r) : "v"(addr));
  return r;
}

__global__ __launch_bounds__(512, 2)
void gemm_band_kernel(const bf16* __restrict__ xb, const bf16* __restrict__ wp,
                      const float* __restrict__ bias, float* __restrict__ out){
  __shared__ __align__(16) bf16 lds[NSTAGE * TILE_ELEMS];   // 120 KiB

  const int bid = blockIdx.x;
  const int mt  = bid & 15;            // fast dim: m-tile (L2/L3 locality)
  const int i   = 31 - (bid >> 4);     // slow dim, descending (LPT)
  const int m0  = mt * BM;
  const int nbK = nb_of(i);
  const int ntiles = nbK * (FEAT / BK);    // 4..32 K32-tiles
  const int lo  = lo_of(i) * FEAT;
  const int Kt  = nbK * FEAT;
  const long wpo = off_of(i);

  const int tid  = threadIdx.x;
  const int lane = tid & 63;
  const int wid  = tid >> 6;           // 0..7
  const int wr   = wid >> 1;           // 0..3 -> 128-row M strip
  const int wc   = wid & 1;            // 0..1 -> 64-col N strip
  const int l31  = lane & 31;          // 32x32 frag row/col
  const int lh   = lane >> 5;          // 0/1 -> k-half of K16 step

  const unsigned ldsBase = lds_addr((void*)lds);

  // -------- loop-invariant LDS read BYTE offsets (superrow swizzle) --------
  // frag (row, kstep kk): 16B slot ks8 = kk*2 + lh within the 64-B row;
  // u = row>>1, q = (((row&1)<<2)|ks8) ^ (u&7), byte = u*128 + q*16.
  unsigned offA0[4], offA1[4], offB0[2], offB1[2];
  #pragma unroll
  for (int mi = 0; mi < 4; ++mi){
    const int row = wr*128 + mi*32 + l31;
    const int u = row >> 1;
    const int q0 = (((row & 1) << 2) | (0*2 + lh)) ^ (u & 7);
    const int q1 = (((row & 1) << 2) | (1*2 + lh)) ^ (u & 7);
    offA0[mi] = (unsigned)(u*128 + q0*16);
    offA1[mi] = (unsigned)(u*128 + q1*16);
  }
  #pragma unroll
  for (int ni = 0; ni < 2; ++ni){
    const int row = wc*64 + ni*32 + l31;
    const int u = row >> 1;
    const int q0 = (((row & 1) << 2) | (0*2 + lh)) ^ (u & 7);
    const int q1 = (((row & 1) << 2) | (1*2 + lh)) ^ (u & 7);
    offB0[ni] = (unsigned)(A_ELEMS*2) + (unsigned)(u*128 + q0*16);
    offB1[ni] = (unsigned)(A_ELEMS*2) + (unsigned)(u*128 + q1*16);
  }

  // -------- staging: pre-permuted global source, linear LDS dest (R5) ------
  const bf16* srcA[4];
  int dstA[4];
  #pragma unroll
  for (int j = 0; j < 4; ++j){
    const int c = j*512 + tid;
    const int u = c >> 3, qq = c & 7;
    const int s8 = qq ^ (u & 7);
    const int r  = 2*u + (s8 >> 2);
    const int sa = s8 & 3;
    srcA[j] = xb + (long)(m0 + r) * INSIZE + lo + sa*8;
    dstA[j] = (j*512 + wid*64) * 8;    // wave-uniform (+lane*16B by HW)
  }
  const bf16* srcB;
  {
    const int c = tid;
    const int u = c >> 3, qq = c & 7;
    const int s8 = qq ^ (u & 7);
    const int r  = 2*u + (s8 >> 2);
    const int sb = s8 & 3;
    srcB = wp + wpo + (long)r * Kt + sb*8;
  }
  const int dstB = A_ELEMS + (wid*64) * 8;

  auto stage = [&](bf16* base, int t){
    gload16(srcA[0] + t*BK, base + dstA[0]);
    gload16(srcA[1] + t*BK, base + dstA[1]);
    gload16(srcA[2] + t*BK, base + dstA[2]);
    gload16(srcA[3] + t*BK, base + dstA[3]);
    gload16(srcB    + t*BK, base + dstB);
  };

  // -------- prologue: fill stages 0,1 (ntiles >= 4 always) -----------------
  stage(lds, 0);
  stage(lds + TILE_ELEMS, 1);

  f32x16 acc[4][2] = {};

  asm volatile("s_waitcnt vmcnt(5)" ::: "memory");   // my stage-0 loads landed
  __builtin_amdgcn_s_barrier();                      // everyone's landed
  asm volatile("" ::: "memory");

  int stC = 0, stPf = 2;
  for (int t = 0; t < ntiles; ++t){
    const unsigned cA = ldsBase + (unsigned)stC * (TILE_ELEMS*2);
    bf16* pfBase = lds + stPf * TILE_ELEMS;
    const bool pf = (t + 2 < ntiles);

    // ---- issue all 12 ds_reads for tile t (kstep0: a,b; kstep1: a,b)
    bf16x8 a00 = ds_read16(cA + offA0[0]);
    bf16x8 a01 = ds_read16(cA + offA0[1]);
    bf16x8 a02 = ds_read16(cA + offA0[2]);
    bf16x8 a03 = ds_read16(cA + offA0[3]);
    bf16x8 b00 = ds_read16(cA + offB0[0]);
    bf16x8 b01 = ds_read16(cA + offB0[1]);
    bf16x8 a10 = ds_read16(cA + offA1[0]);
    bf16x8 a11 = ds_read16(cA + offA1[1]);
    bf16x8 a12 = ds_read16(cA + offA1[2]);
    bf16x8 a13 = ds_read16(cA + offA1[3]);
    bf16x8 b10 = ds_read16(cA + offB1[0]);
    bf16x8 b11 = ds_read16(cA + offB1[1]);

    // ---- issue tile t+2 staging (writes buf t-1, safe per prev barrier)
    if (pf) stage(pfBase, t + 2);

    // ---- my reads done -> MFMA cluster (free-run, no pre-MFMA barrier)
    asm volatile("s_waitcnt lgkmcnt(0)" ::: "memory");
    __builtin_amdgcn_sched_barrier(0);
    __builtin_amdgcn_s_setprio(1);
    acc[0][0] = __builtin_amdgcn_mfma_f32_32x32x16_bf16(a00, b00, acc[0][0], 0,0,0);
    acc[0][1] = __builtin_amdgcn_mfma_f32_32x32x16_bf16(a00, b01, acc[0][1], 0,0,0);
    acc[1][0] = __builtin_amdgcn_mfma_f32_32x32x16_bf16(a01, b00, acc[1][0], 0,0,0);
    acc[1][1] = __builtin_amdgcn_mfma_f32_32x32x16_bf16(a01, b01, acc[1][1], 0,0,0);
    acc[2][0] = __builtin_amdgcn_mfma_f32_32x32x16_bf16(a02, b00, acc[2][0], 0,0,0);
    acc[2][1] = __builtin_amdgcn_mfma_f32_32x32x16_bf16(a02, b01, acc[2][1], 0,0,0);
    acc[3][0] = __builtin_amdgcn_mfma_f32_32x32x16_bf16(a03, b00, acc[3][0], 0,0,0);
    acc[3][1] = __builtin_amdgcn_mfma_f32_32x32x16_bf16(a03, b01, acc[3][1], 0,0,0);
    acc[0][0] = __builtin_amdgcn_mfma_f32_32x32x16_bf16(a10, b10, acc[0][0], 0,0,0);
    acc[0][1] = __builtin_amdgcn_mfma_f32_32x32x16_bf16(a10, b11, acc[0][1], 0,0,0);
    acc[1][0] = __builtin_amdgcn_mfma_f32_32x32x16_bf16(a11, b10, acc[1][0], 0,0,0);
    acc[1][1] = __builtin_amdgcn_mfma_f32_32x32x16_bf16(a11, b11, acc[1][1], 0,0,0);
    acc[2][0] = __builtin_amdgcn_mfma_f32_32x32x16_bf16(a12, b10, acc[2][0], 0,0,0);
    acc[2][1] = __builtin_amdgcn_mfma_f32_32x32x16_bf16(a12, b11, acc[2][1], 0,0,0);
    acc[3][0] = __builtin_amdgcn_mfma_f32_32x32x16_bf16(a13, b10, acc[3][0], 0,0,0);
    acc[3][1] = __builtin_amdgcn_mfma_f32_32x32x16_bf16(a13, b11, acc[3][1], 0,0,0);
    __builtin_amdgcn_s_setprio(0);

    // ---- single per-tile sync: my stage(t+1) retired + everyone ready
    if (t + 1 < ntiles){
      if (pf) asm volatile("s_waitcnt vmcnt(5)" ::: "memory");
      else    asm volatile("s_waitcnt vmcnt(0)" ::: "memory");
      __builtin_amdgcn_s_barrier();
      asm volatile("" ::: "memory");
    }

    stC  = (stC  == NSTAGE-1) ? 0 : stC  + 1;
    stPf = (stPf == NSTAGE-1) ? 0 : stPf + 1;
  }

  // ---- epilogue: 32x32 C/D layout col = lane&31,
  //      row = (reg&3) + 8*(reg>>2) + 4*(lane>>5)   [m74/m101 verified]
  #pragma unroll
  for (int ni = 0; ni < 2; ++ni){
    const int gcol = i*FEAT + wc*64 + ni*32 + l31;
    const float bv = bias[gcol];
    #pragma unroll
    for (int mi = 0; mi < 4; ++mi){
      const int rbase = m0 + wr*128 + mi*32 + 4*lh;
      #pragma unroll
      for (int r = 0; r < 16; ++r){
        const int row = rbase + (r & 3) + 8*(r >> 2);
        out[(long)row * OUTCOLS + gcol] = acc[mi][ni][r] + bv;
      }
    }
  }
}

// ---------------- fallback (tiny ws): naive fp32, band-limited ----------------
__global__ void naive_kernel(const float* __restrict__ x, const float* __restrict__ w,
                             const float* __restrict__ bias, float* __restrict__ out){
  long idx = (long)blockIdx.x * blockDim.x + threadIdx.x;
  int o = (int)(idx & (OUTCOLS - 1));
  int b = (int)(idx >> 12);
  int i = o >> 7;
  int lo = lo_of(i) * FEAT, hi = (i + 1) * FEAT;
  const float* xr = x + (long)b * INSIZE;
  const float* wr = w + (long)o * INSIZE;
  float s = bias[o];
  for (int k = lo; k < hi; k += 4){
    f32x4 xv = *(const f32x4*)(xr + k);
    f32x4 wv = *(const f32x4*)(wr + k);
    s += xv.x*wv.x + xv.y*wv.y + xv.z*wv.z + xv.w*wv.w;
  }
  out[idx] = s;
}

// ---------------- launch ----------------
extern "C" void kernel_launch(void* const* d_in, const int* in_sizes, int n_in,
                              void* d_out, int out_size, void* d_ws, size_t ws_size,
                              hipStream_t stream) {
  const float* x    = (const float*)d_in[0];
  const float* w    = (const float*)d_in[1];
  const float* bias = (const float*)d_in[2];
  float* out = (float*)d_out;

  const size_t x_bytes = (size_t)BATCH * INSIZE * sizeof(bf16);        // 64 MiB
  const size_t w_bytes = (size_t)228 * FEAT * FEAT * sizeof(bf16);     // ~7.5 MiB
  if (ws_size >= x_bytes + w_bytes){
    bf16* xb = (bf16*)d_ws;
    bf16* wp = (bf16*)((char*)d_ws + x_bytes);
    cvt_kernel<<<NT*FEAT + 2048, 256, 0, stream>>>(x, w, xb, wp, (long)BATCH * INSIZE / 4);
    gemm_band_kernel<<<dim3(NT * (BATCH/BM)), 512, 0, stream>>>(xb, wp, bias, out);
  } else {
    naive_kernel<<<(long)BATCH * OUTCOLS / 256, 256, 0, stream>>>(x, w, bias, out);
  }
}